// Round 6
// baseline (339.851 us; speedup 1.0000x reference)
//
#include <hip/hip_runtime.h>
#include <math.h>

#define NB 16
#define NS 4096
#define NH 768
#define NG 16
#define WRAD 15
#define WLEN 31
#define NH4 192     // NH / 4 float4 columns
#define OUTW (1 + NG)
#define NCH 128     // s-chunks per batch
#define CHUNK 32    // NS / NCH

__device__ inline float4 f4max(float4 a, float4 b) {
    return make_float4(fmaxf(a.x, b.x), fmaxf(a.y, b.y), fmaxf(a.z, b.z), fmaxf(a.w, b.w));
}
__device__ inline float4 f4add(float4 a, float4 b) {
    return make_float4(a.x + b.x, a.y + b.y, a.z + b.z, a.w + b.w);
}
__device__ inline float f4dot(float4 a, float4 b) {
    return a.x * b.x + a.y * b.y + a.z * b.z + a.w * b.w;
}

// masked accumulate: mf in {0,1}. max(0,.) clamp downstream makes v*mf
// equivalent to the masked max (invalid rows contribute 0, absorbed).
#define PROC(c, bit)                                                     \
    {                                                                    \
        const float mf = (float)((m >> (bit)) & 1u);                     \
        const float4 vmm = make_float4(c.x * mf, c.y * mf, c.z * mf,     \
                                       c.w * mf);                        \
        mx = f4max(mx, vmm);                                             \
        sm = f4add(sm, vmm);                                             \
    }

// Block reduce (blockDim.x == 192): pad LDS to 256, power-of-2 tree.
__device__ inline float block_reduce_192(float v, float* sbuf) {
    int tid = threadIdx.x;
    sbuf[tid] = v;
    if (tid < 64) sbuf[192 + tid] = 0.0f;
    __syncthreads();
    for (int off = 128; off > 0; off >>= 1) {
        if (tid < off) sbuf[tid] += sbuf[tid + off];
        __syncthreads();
    }
    float r = sbuf[0];
    __syncthreads();
    return r;
}

// ---------------------------------------------------------------------------
// Kernel A (fused): blocks [0, NB*NCH) text partials (streaming, explicit
// 4-row software pipeline, mask-multiply accumulate); blocks
// [NB*NCH, +NB*NG) gap scores (tail filler). 192 thr; thread t = float4 col t.
// R5 lesson: VGPR_Count=32 proved the compiler serialized "8-deep" batches
// (MLP~1-2). Explicit next-batch preload + lean 12-VALU/row body fixes it.
// ---------------------------------------------------------------------------
__global__ __launch_bounds__(192) void fused_kernel(
    const float* __restrict__ seq, const int* __restrict__ tt,
    const int* __restrict__ wm, const int* __restrict__ gids,
    const float* __restrict__ gapW, const float* __restrict__ gapb,
    float* __restrict__ pmax, float* __restrict__ psum,
    int* __restrict__ pcnt, float* __restrict__ out) {
    const int blk = blockIdx.x;
    const int tid = threadIdx.x;

    __shared__ float sbuf[256];
    __shared__ unsigned int s_mask;
    __shared__ int s_gid;

    const float4 zero4 = make_float4(0.f, 0.f, 0.f, 0.f);

    if (blk < NB * NCH) {
        // ---------------- text partial (streaming, pipelined) ----------------
        const int b = blk / NCH;
        const int ss = blk % NCH;
        const int s0 = ss * CHUNK;

        if (tid < 64) {  // wave 0: 32 mask bits for this chunk (lanes >=32 -> 0)
            bool v = false;
            if (tid < CHUNK) {
                const int s = s0 + tid;
                v = (tt[b * NS + s] == 0) && (wm[b * NS + s] != 0);
            }
            unsigned long long bm = __ballot(v);
            if (tid == 0) s_mask = (unsigned int)bm;
        }
        __syncthreads();
        const unsigned int m = s_mask;

        const float4* base = ((const float4*)seq) + (size_t)(b * NS + s0) * NH4 + tid;
        float4 mx = zero4;  // >=0 always; final max(0,.) makes this exact
        float4 sm = zero4;

        float4 c0 = base[0 * NH4];
        float4 c1 = base[1 * NH4];
        float4 c2 = base[2 * NH4];
        float4 c3 = base[3 * NH4];
        int j = 0;
#pragma unroll 2
        for (; j < CHUNK - 4; j += 4) {
            const float4* nb = base + (size_t)(j + 4) * NH4;
            float4 n0 = nb[0 * NH4];
            float4 n1 = nb[1 * NH4];
            float4 n2 = nb[2 * NH4];
            float4 n3 = nb[3 * NH4];
            PROC(c0, j + 0);
            PROC(c1, j + 1);
            PROC(c2, j + 2);
            PROC(c3, j + 3);
            c0 = n0; c1 = n1; c2 = n2; c3 = n3;
        }
        PROC(c0, j + 0);
        PROC(c1, j + 1);
        PROC(c2, j + 2);
        PROC(c3, j + 3);

        const size_t o = ((size_t)(b * NCH + ss)) * NH4 + tid;
        ((float4*)pmax)[o] = mx;
        ((float4*)psum)[o] = sm;
        if (tid == 0) pcnt[b * NCH + ss] = __popc(m);
    } else {
        // ---------------- gap score ----------------
        const int bg = blk - NB * NCH;
        const int b = bg >> 4;
        const int g = bg & 15;

        if (tid == 0) s_gid = gids[b * NG + g];
        __syncthreads();
        const int gi = s_gid;

        if (tid < 64) {  // wave 0 computes the 31 validity bits
            bool v = false;
            if (tid < WLEN) {
                const int idx = gi - WRAD + tid;
                v = (idx >= 0) && (idx < NS) && (tt[b * NS + idx] == 0) &&
                    (wm[b * NS + idx] != 0);
            }
            unsigned long long bm = __ballot(v);
            if (tid == 0) s_mask = (unsigned int)bm;
        }
        __syncthreads();
        const unsigned int m = s_mask;
        const float count = (float)__popc(m);

        const float4* rowbase = ((const float4*)seq) + (size_t)b * NS * NH4;
        const float4 gv = rowbase[(size_t)gi * NH4 + tid];

        float4 mx = zero4;
        float4 sm = zero4;
#pragma unroll 4
        for (int j = 0; j < WLEN; ++j) {
            int idx = gi - WRAD + j;
            idx = idx < 0 ? 0 : (idx > NS - 1 ? NS - 1 : idx);
            const float4 c = rowbase[(size_t)idx * NH4 + tid];  // unconditional
            PROC(c, j);
        }
        const float4 wmax = mx;  // already clamped at 0 by construction
        // plain division: count==0 -> 0/0 = NaN, matching the reference.
        const float4 wavg = make_float4(sm.x / count, sm.y / count,
                                        sm.z / count, sm.w / count);

        const float4* w0 = (const float4*)gapW;
        const float4* w1 = (const float4*)(gapW + NH);
        const float4* w2 = (const float4*)(gapW + 2 * NH);
        float part = f4dot(gv, w0[tid]) + f4dot(wmax, w1[tid]) + f4dot(wavg, w2[tid]);
        float total = block_reduce_192(part, sbuf);
        if (tid == 0) out[b * OUTW + 1 + g] = total + gapb[0];
    }
}

// ---------------------------------------------------------------------------
// Kernel B: per-batch cls. Combines NCH partials + counts, fused dot.
// ---------------------------------------------------------------------------
__global__ __launch_bounds__(192) void cls_kernel(
    const float* __restrict__ pooled, const float* __restrict__ pmax,
    const float* __restrict__ psum, const int* __restrict__ pcnt,
    const float* __restrict__ clsW, const float* __restrict__ clsb,
    float* __restrict__ out) {
    const int b = blockIdx.x;
    const int tid = threadIdx.x;
    __shared__ float sbuf[256];

    float c = (tid < NCH) ? (float)pcnt[b * NCH + tid] : 0.f;
    const float count = block_reduce_192(c, sbuf);

    const float4* pm4 = (const float4*)pmax;
    const float4* ps4 = (const float4*)psum;
    float4 mx = make_float4(0.f, 0.f, 0.f, 0.f);  // partials are >= 0
    float4 sm = make_float4(0.f, 0.f, 0.f, 0.f);
#pragma unroll 8
    for (int ch = 0; ch < NCH; ++ch) {
        const size_t o = ((size_t)(b * NCH + ch)) * NH4 + tid;
        mx = f4max(mx, pm4[o]);
        sm = f4add(sm, ps4[o]);
    }
    const float4 tmax = mx;  // max(0,.) already folded in
    const float4 tavg = make_float4(sm.x / count, sm.y / count,
                                    sm.z / count, sm.w / count);

    const float4* p4 = (const float4*)(pooled + (size_t)b * NH);
    const float4* w0 = (const float4*)clsW;
    const float4* w1 = (const float4*)(clsW + NH);
    const float4* w2 = (const float4*)(clsW + 2 * NH);
    float part = f4dot(p4[tid], w0[tid]) + f4dot(tmax, w1[tid]) + f4dot(tavg, w2[tid]);
    float total = block_reduce_192(part, sbuf);
    if (tid == 0) out[b * OUTW + 0] = total + clsb[0];
}

extern "C" void kernel_launch(void* const* d_in, const int* in_sizes, int n_in,
                              void* d_out, int out_size, void* d_ws, size_t ws_size,
                              hipStream_t stream) {
    const float* seq    = (const float*)d_in[0];  // [B,S,H] fp32
    const float* pooled = (const float*)d_in[1];  // [B,H]
    const int*   tt     = (const int*)d_in[2];    // [B,S]
    const int*   wm     = (const int*)d_in[3];    // [B,S]
    const int*   gids   = (const int*)d_in[4];    // [B,G]
    const float* gapW   = (const float*)d_in[5];  // [3H]
    const float* gapb   = (const float*)d_in[6];  // scalar
    const float* clsW   = (const float*)d_in[7];  // [3H]
    const float* clsb   = (const float*)d_in[8];  // scalar
    float* out = (float*)d_out;

    // ws layout: pmax | psum | pcnt (all written by kernel A before B reads)
    float* pmax = (float*)d_ws;
    float* psum = pmax + (size_t)NB * NCH * NH;
    int*   pcnt = (int*)(psum + (size_t)NB * NCH * NH);

    fused_kernel<<<NB * NCH + NB * NG, 192, 0, stream>>>(
        seq, tt, wm, gids, gapW, gapb, pmax, psum, pcnt, out);
    cls_kernel<<<NB, 192, 0, stream>>>(pooled, pmax, psum, pcnt, clsW, clsb, out);
}